// Round 1
// baseline (511.500 us; speedup 1.0000x reference)
//
#include <hip/hip_runtime.h>
#include <stdint.h>

typedef short short8 __attribute__((ext_vector_type(8)));
typedef float floatx16 __attribute__((ext_vector_type(16)));

// Problem constants
constexpr int CB = 8;      // batch
constexpr int CT = 8192;   // tokens
constexpr int CI = 512;    // in features (GEMM K-dim)
constexpr int CE = 16;     // experts
constexpr int CK = 1024;   // gathered rows per (b,e) (GEMM M-dim)
constexpr int CJ = 512;    // out features (GEMM N-dim)

__device__ __forceinline__ uint32_t f2bf(float f) {
    union { float f; uint32_t u; } c; c.f = f;
    return (c.u + 0x7fffu + ((c.u >> 16) & 1u)) >> 16;   // RNE to bf16 bits
}
__device__ __forceinline__ uint32_t pack2(float lo, float hi) {
    return f2bf(lo) | (f2bf(hi) << 16);
}

// Block: 256 threads (4 waves). Output tile 128(M) x 128(N), BK=32.
// Wave tile 64x64 via 2x2 of v_mfma_f32_32x32x16_bf16.
__global__ __launch_bounds__(256, 2) void eg_kernel(
    const float* __restrict__ x, const int* __restrict__ Ind,
    const float* __restrict__ W, float* __restrict__ out)
{
    constexpr int AS_STRIDE = 20;   // words per A row: 40 bf16 (32 used + 8 pad) = 80B, 16B-aligned
    constexpr int BS_STRIDE = 132;  // words per B kp-row: 128 n-words + 4 pad = 528B, 16B-aligned

    __shared__ __align__(16) uint32_t As[128 * AS_STRIDE]; // 10240 B, bf16 [m][k]
    __shared__ __align__(16) uint32_t Bs[16 * BS_STRIDE];  //  8448 B, k-pair-packed bf16 [kp][n]
    __shared__ int s_idx[128];

    const int t = threadIdx.x;
    const int z = blockIdx.z;            // b*E + e
    const int e = z & (CE - 1);
    const int b = z >> 4;
    const int mtile = blockIdx.y;        // 0..7
    const int ntile = blockIdx.x;        // 0..3

    if (t < 128) s_idx[t] = Ind[z * CK + mtile * 128 + t];
    __syncthreads();

    // A staging: 2 threads per gathered row, 16 consecutive floats each
    const int am = t >> 1;               // 0..127
    const int ah = t & 1;
    const float* aptr = x + ((size_t)b * CT + s_idx[am]) * CI + ah * 16;
    uint32_t* adst = &As[am * AS_STRIDE + ah * 8];

    // B staging: coalesced rows of W, transpose+pack k-pairs
    const int bjc = t & 31;              // j-word chunk (4 packed words)
    const int bkp = t >> 5;              // kp base 0..7 (+8 on 2nd iter)
    const float* wptr = W + (size_t)e * CI * CJ + ntile * 128 + bjc * 4;

    // compute-side lane mapping
    const int ln = t & 63, wv = t >> 6;
    const int wm = (wv >> 1) * 64, wn = (wv & 1) * 64;
    const int lrow = ln & 31;            // m (A-frag) / n (B-frag) / col (C)
    const int lh = ln >> 5;              // wave half

    const floatx16 fz = {0.f,0.f,0.f,0.f,0.f,0.f,0.f,0.f,0.f,0.f,0.f,0.f,0.f,0.f,0.f,0.f};
    floatx16 acc[2][2] = {{fz, fz}, {fz, fz}};

    for (int kt = 0; kt < CI / 32; ++kt) {
        // ---- stage A tile (128 rows x 32 k, fp32 -> bf16)
        {
            const float4* ap = (const float4*)(aptr + kt * 32);
            float4 a0 = ap[0], a1 = ap[1], a2 = ap[2], a3 = ap[3];
            uint4 w0 = make_uint4(pack2(a0.x, a0.y), pack2(a0.z, a0.w),
                                  pack2(a1.x, a1.y), pack2(a1.z, a1.w));
            uint4 w1 = make_uint4(pack2(a2.x, a2.y), pack2(a2.z, a2.w),
                                  pack2(a3.x, a3.y), pack2(a3.z, a3.w));
            ((uint4*)adst)[0] = w0;
            *((uint4*)(adst + 4)) = w1;
        }
        // ---- stage B tile (32 k x 128 n, fp32 -> transposed k-pair-packed bf16)
        #pragma unroll
        for (int i = 0; i < 2; ++i) {
            const int kp = bkp + i * 8;                      // 0..15
            const float* wp = wptr + (size_t)(kt * 32 + kp * 2) * CJ;
            float4 r0 = *(const float4*)(wp);                // k even
            float4 r1 = *(const float4*)(wp + CJ);           // k odd
            uint4 wq = make_uint4(pack2(r0.x, r1.x), pack2(r0.y, r1.y),
                                  pack2(r0.z, r1.z), pack2(r0.w, r1.w));
            *((uint4*)&Bs[kp * BS_STRIDE + bjc * 4]) = wq;
        }
        __syncthreads();

        // ---- two K=16 MFMA sub-steps
        #pragma unroll
        for (int sub = 0; sub < 2; ++sub) {
            short8 af[2], bf[2];
            #pragma unroll
            for (int mt = 0; mt < 2; ++mt)
                af[mt] = *(const short8*)&As[(wm + mt * 32 + lrow) * AS_STRIDE + sub * 8 + lh * 4];
            #pragma unroll
            for (int nt = 0; nt < 2; ++nt) {
                const int n = wn + nt * 32 + lrow;
                const int kp0 = sub * 8 + lh * 4;
                union { uint32_t u[4]; short8 s; } cv;
                cv.u[0] = Bs[(kp0 + 0) * BS_STRIDE + n];
                cv.u[1] = Bs[(kp0 + 1) * BS_STRIDE + n];
                cv.u[2] = Bs[(kp0 + 2) * BS_STRIDE + n];
                cv.u[3] = Bs[(kp0 + 3) * BS_STRIDE + n];
                bf[nt] = cv.s;
            }
            #pragma unroll
            for (int mt = 0; mt < 2; ++mt)
                #pragma unroll
                for (int nt = 0; nt < 2; ++nt)
                    acc[mt][nt] = __builtin_amdgcn_mfma_f32_32x32x16_bf16(
                        af[mt], bf[nt], acc[mt][nt], 0, 0, 0);
        }
        __syncthreads();
    }

    // ---- epilogue: C/D layout col=lane&31, row=(r&3)+8*(r>>2)+4*(lane>>5)
    const size_t obase = (size_t)z * CK * CJ;
    #pragma unroll
    for (int mt = 0; mt < 2; ++mt) {
        const int gm0 = mtile * 128 + wm + mt * 32 + lh * 4;
        #pragma unroll
        for (int nt = 0; nt < 2; ++nt) {
            const int gn = ntile * 128 + wn + nt * 32 + lrow;
            #pragma unroll
            for (int r = 0; r < 16; ++r) {
                const int gm = gm0 + (r & 3) + 8 * (r >> 2);
                out[obase + (size_t)gm * CJ + gn] = acc[mt][nt][r];
            }
        }
    }
}

extern "C" void kernel_launch(void* const* d_in, const int* in_sizes, int n_in,
                              void* d_out, int out_size, void* d_ws, size_t ws_size,
                              hipStream_t stream) {
    const float* x   = (const float*)d_in[0];
    const int*   Ind = (const int*)d_in[1];
    const float* W   = (const float*)d_in[2];
    float* out = (float*)d_out;

    dim3 grid(CJ / 128, CK / 128, CB * CE);   // (ntiles=4, mtiles=8, b*e=128) = 4096 blocks
    dim3 block(256);
    hipLaunchKernelGGL(eg_kernel, grid, block, 0, stream, x, Ind, W, out);
}